// Round 1
// baseline (713.957 us; speedup 1.0000x reference)
//
#include <hip/hip_runtime.h>
#include <math.h>

#define NODES 50000
#define EDGES 800000
#define NB_SCAN ((NODES + 1023) / 1024)

__device__ __forceinline__ float lrelu02(float x){ return x > 0.f ? x : 0.2f * x; }

// ---------------- CSR build ----------------

__global__ __launch_bounds__(256) void gat_zero(int* __restrict__ p, int n){
  int i = blockIdx.x * 256 + threadIdx.x;
  if (i < n) p[i] = 0;
}

__global__ __launch_bounds__(256) void gat_hist(const int* __restrict__ ei, int* __restrict__ cnt){
  int e = blockIdx.x * 256 + threadIdx.x;
  if (e < EDGES) atomicAdd(&cnt[ei[EDGES + e]], 1);
}

__global__ __launch_bounds__(256) void gat_blocksum(const int* __restrict__ cnt, int* __restrict__ bsums){
  __shared__ int sd[256];
  int t = threadIdx.x, b = blockIdx.x;
  int base = b * 1024 + t * 4, s = 0;
  #pragma unroll
  for (int j = 0; j < 4; j++){ int i = base + j; if (i < NODES) s += cnt[i]; }
  sd[t] = s; __syncthreads();
  for (int o = 128; o > 0; o >>= 1){ if (t < o) sd[t] += sd[t + o]; __syncthreads(); }
  if (t == 0) bsums[b] = sd[0];
}

__global__ void gat_scan_bsums(int* bsums, int nb){
  if (threadIdx.x == 0 && blockIdx.x == 0){
    int run = 0;
    for (int i = 0; i < nb; i++){ int v = bsums[i]; bsums[i] = run; run += v; }
  }
}

__global__ __launch_bounds__(256) void gat_rowptr(int* __restrict__ cnt, const int* __restrict__ bsums,
                                                  int* __restrict__ row_ptr){
  __shared__ int sd[256];
  int t = threadIdx.x, b = blockIdx.x;
  int base = b * 1024 + t * 4;
  int c[4]; int s = 0;
  #pragma unroll
  for (int j = 0; j < 4; j++){
    int i = base + j;
    c[j] = (i < NODES) ? cnt[i] : 0;
    s += c[j];
    if (i < NODES) cnt[i] = 0;   // reset for scatter fill counters
  }
  sd[t] = s; __syncthreads();
  for (int o = 1; o < 256; o <<= 1){
    int v = (t >= o) ? sd[t - o] : 0;
    __syncthreads();
    if (t >= o) sd[t] += v;
    __syncthreads();
  }
  int off = bsums[b] + sd[t] - s;   // exclusive prefix for this thread
  #pragma unroll
  for (int j = 0; j < 4; j++){
    int i = base + j;
    if (i < NODES){ row_ptr[i] = off; off += c[j]; }
  }
  if (b == 0 && t == 0) row_ptr[NODES] = EDGES;
}

__global__ __launch_bounds__(256) void gat_scatter(const int* __restrict__ ei, const int* __restrict__ row_ptr,
                                                    int* __restrict__ fill, int* __restrict__ col){
  int e = blockIdx.x * 256 + threadIdx.x;
  if (e < EDGES){
    int s = ei[e], d = ei[EDGES + e];
    int pos = row_ptr[d] + atomicAdd(&fill[d], 1);
    col[pos] = s;
  }
}

// ---------------- fp32 GEMM: C[M,N] = A[M,K] @ B[K,N]; N % 64 == 0, K % 16 == 0 ----------------

__global__ __launch_bounds__(256) void gat_gemm(const float* __restrict__ A, const float* __restrict__ B,
                                                 float* __restrict__ C, int M, int K, int N){
  __shared__ float As[16][65];   // [k][m]
  __shared__ float Bs[16][64];   // [k][n]
  int tid = threadIdx.x;
  int bm = blockIdx.y * 64, bn = blockIdx.x * 64;
  int tx = tid & 15, ty = tid >> 4;

  int ar = tid >> 2;          // 0..63 (row within tile)
  int ac = (tid & 3) * 4;     // 0,4,8,12 (k within tile)
  int br = tid >> 4;          // 0..15 (k within tile)
  int bc = (tid & 15) * 4;    // 0..60 (n within tile)
  int arow = bm + ar;
  bool avalid = arow < M;

  float acc[4][4] = {};

  for (int k0 = 0; k0 < K; k0 += 16){
    float4 av = avalid ? *(const float4*)&A[(size_t)arow * K + k0 + ac] : make_float4(0.f,0.f,0.f,0.f);
    float4 bv = *(const float4*)&B[(size_t)(k0 + br) * N + bn + bc];
    __syncthreads();
    As[ac + 0][ar] = av.x; As[ac + 1][ar] = av.y; As[ac + 2][ar] = av.z; As[ac + 3][ar] = av.w;
    *(float4*)&Bs[br][bc] = bv;
    __syncthreads();
    #pragma unroll
    for (int k = 0; k < 16; k++){
      float a0 = As[k][ty*4+0], a1 = As[k][ty*4+1], a2 = As[k][ty*4+2], a3 = As[k][ty*4+3];
      float b0 = Bs[k][tx*4+0], b1 = Bs[k][tx*4+1], b2 = Bs[k][tx*4+2], b3 = Bs[k][tx*4+3];
      acc[0][0] += a0*b0; acc[0][1] += a0*b1; acc[0][2] += a0*b2; acc[0][3] += a0*b3;
      acc[1][0] += a1*b0; acc[1][1] += a1*b1; acc[1][2] += a1*b2; acc[1][3] += a1*b3;
      acc[2][0] += a2*b0; acc[2][1] += a2*b1; acc[2][2] += a2*b2; acc[2][3] += a2*b3;
      acc[3][0] += a3*b0; acc[3][1] += a3*b1; acc[3][2] += a3*b2; acc[3][3] += a3*b3;
    }
  }
  #pragma unroll
  for (int i = 0; i < 4; i++){
    int r = bm + ty*4 + i;
    if (r < M){
      float4 v = make_float4(acc[i][0], acc[i][1], acc[i][2], acc[i][3]);
      *(float4*)&C[(size_t)r * N + bn + tx*4] = v;
    }
  }
}

// ---------------- attention coefficients: asrc[n,h] = <h[n,h,:], a_src[h,:]> ----------------

template<int H>
__global__ __launch_bounds__(256) void gat_attn(const float* __restrict__ h, const float* __restrict__ a_src,
                                                 const float* __restrict__ a_dst,
                                                 float* __restrict__ asrc, float* __restrict__ adst, int N){
  int lane = threadIdx.x & 63;
  int wid = threadIdx.x >> 6;
  int n = blockIdx.x * 4 + wid;
  if (n >= N) return;
  const int HC = H * 64;
  #pragma unroll
  for (int q = 0; q < H; q++){
    float v = h[(size_t)n * HC + q * 64 + lane];
    float s1 = v * a_src[q * 64 + lane];
    float s2 = v * a_dst[q * 64 + lane];
    #pragma unroll
    for (int o = 32; o > 0; o >>= 1){ s1 += __shfl_xor(s1, o); s2 += __shfl_xor(s2, o); }
    if (lane == 0){ asrc[n * H + q] = s1; adst[n * H + q] = s2; }
  }
}

// ---------------- CSR aggregate: softmax (m=0) + message sum + bias (+ELU) ----------------

template<int H, bool DOELU>
__global__ __launch_bounds__(256) void gat_aggregate(const float* __restrict__ h, const float* __restrict__ asrc,
                                                      const float* __restrict__ adst,
                                                      const int* __restrict__ row_ptr, const int* __restrict__ col,
                                                      const float* __restrict__ bias, float* __restrict__ out, int N){
  int lane = threadIdx.x & 63;
  int wid = threadIdx.x >> 6;
  int d = blockIdx.x * 4 + wid;
  if (d >= N) return;
  const int HC = H * 64;

  float ad[H], acc[H], den[H];
  #pragma unroll
  for (int q = 0; q < H; q++) ad[q] = adst[d * H + q];

  // self loop
  #pragma unroll
  for (int q = 0; q < H; q++){
    float ex = expf(lrelu02(asrc[d * H + q] + ad[q]));
    den[q] = ex;
    acc[q] = ex * h[(size_t)d * HC + q * 64 + lane];
  }

  int e0 = row_ptr[d], e1 = row_ptr[d + 1];
  for (int e = e0; e < e1; ++e){
    int s = col[e];
    const float* hs = &h[(size_t)s * HC];
    #pragma unroll
    for (int q = 0; q < H; q++){
      float ex = expf(lrelu02(asrc[s * H + q] + ad[q]));
      den[q] += ex;
      acc[q] += ex * hs[q * 64 + lane];
    }
  }

  #pragma unroll
  for (int q = 0; q < H; q++){
    float o = acc[q] / (den[q] + 1e-16f) + bias[q * 64 + lane];
    if (DOELU) o = o > 0.f ? o : expm1f(o);
    out[(size_t)d * HC + q * 64 + lane] = o;
  }
}

// ---------------- launch ----------------

extern "C" void kernel_launch(void* const* d_in, const int* in_sizes, int n_in,
                              void* d_out, int out_size, void* d_ws, size_t ws_size,
                              hipStream_t stream) {
  const float* x   = (const float*)d_in[0];
  const int*   ei  = (const int*)  d_in[1];
  const float* W0  = (const float*)d_in[2];
  const float* as0 = (const float*)d_in[3];
  const float* ad0 = (const float*)d_in[4];
  const float* b0  = (const float*)d_in[5];
  const float* W1  = (const float*)d_in[6];
  const float* as1 = (const float*)d_in[7];
  const float* ad1 = (const float*)d_in[8];
  const float* b1  = (const float*)d_in[9];
  const float* W2  = (const float*)d_in[10];
  const float* as2 = (const float*)d_in[11];
  const float* ad2 = (const float*)d_in[12];
  const float* b2  = (const float*)d_in[13];
  float* out = (float*)d_out;

  auto al = [](size_t v){ return (v + 255) & ~(size_t)255; };
  char* p = (char*)d_ws;
  int*   row_ptr = (int*)p;   p += al((NODES + 1) * sizeof(int));
  int*   cnt     = (int*)p;   p += al(NODES * sizeof(int));
  int*   bsums   = (int*)p;   p += al(64 * sizeof(int));
  int*   col     = (int*)p;   p += al(EDGES * sizeof(int));
  float* asrc    = (float*)p; p += al(NODES * 4 * sizeof(float));
  float* adst    = (float*)p; p += al(NODES * 4 * sizeof(float));
  float* actb    = (float*)p; p += al((size_t)NODES * 256 * sizeof(float));
  float* hb      = (float*)p; p += al((size_t)NODES * 256 * sizeof(float));

  // ---- CSR build (by dst) ----
  gat_zero<<<(NODES + 255) / 256, 256, 0, stream>>>(cnt, NODES);
  gat_hist<<<(EDGES + 255) / 256, 256, 0, stream>>>(ei, cnt);
  gat_blocksum<<<NB_SCAN, 256, 0, stream>>>(cnt, bsums);
  gat_scan_bsums<<<1, 64, 0, stream>>>(bsums, NB_SCAN);
  gat_rowptr<<<NB_SCAN, 256, 0, stream>>>(cnt, bsums, row_ptr);
  gat_scatter<<<(EDGES + 255) / 256, 256, 0, stream>>>(ei, row_ptr, cnt, col);

  const int nodeBlocks = (NODES + 3) / 4;

  // ---- Layer 0: x[50000,64] @ W0[64,256] ----
  gat_gemm<<<dim3(256 / 64, (NODES + 63) / 64), 256, 0, stream>>>(x, W0, hb, NODES, 64, 256);
  gat_attn<4><<<nodeBlocks, 256, 0, stream>>>(hb, as0, ad0, asrc, adst, NODES);
  gat_aggregate<4, true><<<nodeBlocks, 256, 0, stream>>>(hb, asrc, adst, row_ptr, col, b0, actb, NODES);

  // ---- Layer 1: actb[50000,256] @ W1[256,256] ----
  gat_gemm<<<dim3(256 / 64, (NODES + 63) / 64), 256, 0, stream>>>(actb, W1, hb, NODES, 256, 256);
  gat_attn<4><<<nodeBlocks, 256, 0, stream>>>(hb, as1, ad1, asrc, adst, NODES);
  gat_aggregate<4, true><<<nodeBlocks, 256, 0, stream>>>(hb, asrc, adst, row_ptr, col, b1, actb, NODES);

  // ---- Layer 2: actb[50000,256] @ W2[256,64], 1 head, no ELU, to d_out ----
  gat_gemm<<<dim3(64 / 64, (NODES + 63) / 64), 256, 0, stream>>>(actb, W2, hb, NODES, 256, 64);
  gat_attn<1><<<nodeBlocks, 256, 0, stream>>>(hb, as2, ad2, asrc, adst, NODES);
  gat_aggregate<1, false><<<nodeBlocks, 256, 0, stream>>>(hb, asrc, adst, row_ptr, col, b2, out, NODES);
}

// Round 2
// 629.876 us; speedup vs baseline: 1.1335x; 1.1335x over previous
//
#include <hip/hip_runtime.h>
#include <hip/hip_fp16.h>
#include <math.h>

#define NODES 50000
#define EDGES 800000
#define NB_SCAN ((NODES + 1023) / 1024)

__device__ __forceinline__ float lrelu02(float x){ return x > 0.f ? x : 0.2f * x; }

// ---------------- CSR build ----------------

__global__ __launch_bounds__(256) void gat_zero(int* __restrict__ p, int n){
  int i = blockIdx.x * 256 + threadIdx.x;
  if (i < n) p[i] = 0;
}

__global__ __launch_bounds__(256) void gat_hist(const int* __restrict__ ei, int* __restrict__ cnt){
  int e = blockIdx.x * 256 + threadIdx.x;
  if (e < EDGES) atomicAdd(&cnt[ei[EDGES + e]], 1);
}

__global__ __launch_bounds__(256) void gat_blocksum(const int* __restrict__ cnt, int* __restrict__ bsums){
  __shared__ int sd[256];
  int t = threadIdx.x, b = blockIdx.x;
  int base = b * 1024 + t * 4, s = 0;
  #pragma unroll
  for (int j = 0; j < 4; j++){ int i = base + j; if (i < NODES) s += cnt[i]; }
  sd[t] = s; __syncthreads();
  for (int o = 128; o > 0; o >>= 1){ if (t < o) sd[t] += sd[t + o]; __syncthreads(); }
  if (t == 0) bsums[b] = sd[0];
}

__global__ void gat_scan_bsums(int* bsums, int nb){
  if (threadIdx.x == 0 && blockIdx.x == 0){
    int run = 0;
    for (int i = 0; i < nb; i++){ int v = bsums[i]; bsums[i] = run; run += v; }
  }
}

__global__ __launch_bounds__(256) void gat_rowptr(int* __restrict__ cnt, const int* __restrict__ bsums,
                                                  int* __restrict__ row_ptr){
  __shared__ int sd[256];
  int t = threadIdx.x, b = blockIdx.x;
  int base = b * 1024 + t * 4;
  int c[4]; int s = 0;
  #pragma unroll
  for (int j = 0; j < 4; j++){
    int i = base + j;
    c[j] = (i < NODES) ? cnt[i] : 0;
    s += c[j];
    if (i < NODES) cnt[i] = 0;   // reset for scatter fill counters
  }
  sd[t] = s; __syncthreads();
  for (int o = 1; o < 256; o <<= 1){
    int v = (t >= o) ? sd[t - o] : 0;
    __syncthreads();
    if (t >= o) sd[t] += v;
    __syncthreads();
  }
  int off = bsums[b] + sd[t] - s;   // exclusive prefix for this thread
  #pragma unroll
  for (int j = 0; j < 4; j++){
    int i = base + j;
    if (i < NODES){ row_ptr[i] = off; off += c[j]; }
  }
  if (b == 0 && t == 0) row_ptr[NODES] = EDGES;
}

__global__ __launch_bounds__(256) void gat_scatter(const int* __restrict__ ei, const int* __restrict__ row_ptr,
                                                    int* __restrict__ fill, int* __restrict__ col,
                                                    int* __restrict__ dstarr){
  int e = blockIdx.x * 256 + threadIdx.x;
  if (e < EDGES){
    int s = ei[e], d = ei[EDGES + e];
    int pos = row_ptr[d] + atomicAdd(&fill[d], 1);
    col[pos] = s;
    dstarr[pos] = d;
  }
}

// ---------------- fp32 GEMM, fp16 output: C[M,N] = A[M,K] @ B[K,N] ----------------

__global__ __launch_bounds__(256) void gat_gemm_h(const float* __restrict__ A, const float* __restrict__ B,
                                                   __half* __restrict__ C, int M, int K, int N){
  __shared__ float As[16][65];   // [k][m]
  __shared__ float Bs[16][64];   // [k][n]
  int tid = threadIdx.x;
  int bm = blockIdx.y * 64, bn = blockIdx.x * 64;
  int tx = tid & 15, ty = tid >> 4;

  int ar = tid >> 2;          // 0..63 (row within tile)
  int ac = (tid & 3) * 4;     // 0,4,8,12 (k within tile)
  int br = tid >> 4;          // 0..15 (k within tile)
  int bc = (tid & 15) * 4;    // 0..60 (n within tile)
  int arow = bm + ar;
  bool avalid = arow < M;

  float acc[4][4] = {};

  for (int k0 = 0; k0 < K; k0 += 16){
    float4 av = avalid ? *(const float4*)&A[(size_t)arow * K + k0 + ac] : make_float4(0.f,0.f,0.f,0.f);
    float4 bv = *(const float4*)&B[(size_t)(k0 + br) * N + bn + bc];
    __syncthreads();
    As[ac + 0][ar] = av.x; As[ac + 1][ar] = av.y; As[ac + 2][ar] = av.z; As[ac + 3][ar] = av.w;
    *(float4*)&Bs[br][bc] = bv;
    __syncthreads();
    #pragma unroll
    for (int k = 0; k < 16; k++){
      float a0 = As[k][ty*4+0], a1 = As[k][ty*4+1], a2 = As[k][ty*4+2], a3 = As[k][ty*4+3];
      float b0 = Bs[k][tx*4+0], b1 = Bs[k][tx*4+1], b2 = Bs[k][tx*4+2], b3 = Bs[k][tx*4+3];
      acc[0][0] += a0*b0; acc[0][1] += a0*b1; acc[0][2] += a0*b2; acc[0][3] += a0*b3;
      acc[1][0] += a1*b0; acc[1][1] += a1*b1; acc[1][2] += a1*b2; acc[1][3] += a1*b3;
      acc[2][0] += a2*b0; acc[2][1] += a2*b1; acc[2][2] += a2*b2; acc[2][3] += a2*b3;
      acc[3][0] += a3*b0; acc[3][1] += a3*b1; acc[3][2] += a3*b2; acc[3][3] += a3*b3;
    }
  }
  #pragma unroll
  for (int i = 0; i < 4; i++){
    int r = bm + ty*4 + i;
    if (r < M){
      __half2 h01 = __floats2half2_rn(acc[i][0], acc[i][1]);
      __half2 h23 = __floats2half2_rn(acc[i][2], acc[i][3]);
      uint2 v = make_uint2(*(const unsigned int*)&h01, *(const unsigned int*)&h23);
      *(uint2*)&C[(size_t)r * N + bn + tx*4] = v;
    }
  }
}

// ---------------- attention coefficients from fp16 h ----------------

template<int H>
__global__ __launch_bounds__(256) void gat_attn(const __half* __restrict__ h, const float* __restrict__ a_src,
                                                 const float* __restrict__ a_dst,
                                                 float* __restrict__ asrc, float* __restrict__ adst, int N){
  int lane = threadIdx.x & 63;
  int wid = threadIdx.x >> 6;
  int n = blockIdx.x * 4 + wid;
  if (n >= N) return;
  const int HC = H * 64;
  #pragma unroll
  for (int q = 0; q < H; q++){
    float v = __half2float(h[(size_t)n * HC + q * 64 + lane]);
    float s1 = v * a_src[q * 64 + lane];
    float s2 = v * a_dst[q * 64 + lane];
    #pragma unroll
    for (int o = 32; o > 0; o >>= 1){ s1 += __shfl_xor(s1, o); s2 += __shfl_xor(s2, o); }
    if (lane == 0){ asrc[n * H + q] = s1; adst[n * H + q] = s2; }
  }
}

// ---------------- edge-parallel exp precompute ----------------

__global__ __launch_bounds__(256) void gat_edge_exp4(const int* __restrict__ col, const int* __restrict__ dstarr,
                                                      const float* __restrict__ asrc, const float* __restrict__ adst,
                                                      float* __restrict__ exf, float* __restrict__ exself){
  int i = blockIdx.x * 256 + threadIdx.x;
  if (i < EDGES){
    int s = col[i], d = dstarr[i];
    float4 a = *(const float4*)&asrc[s * 4];
    float4 b = *(const float4*)&adst[d * 4];
    float4 r;
    r.x = expf(lrelu02(a.x + b.x));
    r.y = expf(lrelu02(a.y + b.y));
    r.z = expf(lrelu02(a.z + b.z));
    r.w = expf(lrelu02(a.w + b.w));
    *(float4*)&exf[(size_t)i * 4] = r;
  } else if (i < EDGES + NODES){
    int n = i - EDGES;
    float4 a = *(const float4*)&asrc[n * 4];
    float4 b = *(const float4*)&adst[n * 4];
    float4 r;
    r.x = expf(lrelu02(a.x + b.x));
    r.y = expf(lrelu02(a.y + b.y));
    r.z = expf(lrelu02(a.z + b.z));
    r.w = expf(lrelu02(a.w + b.w));
    *(float4*)&exself[n * 4] = r;
  }
}

__global__ __launch_bounds__(256) void gat_edge_exp1(const int* __restrict__ col, const int* __restrict__ dstarr,
                                                      const float* __restrict__ asrc, const float* __restrict__ adst,
                                                      float* __restrict__ exf, float* __restrict__ exself){
  int i = blockIdx.x * 256 + threadIdx.x;
  if (i < EDGES){
    exf[i] = expf(lrelu02(asrc[col[i]] + adst[dstarr[i]]));
  } else if (i < EDGES + NODES){
    int n = i - EDGES;
    exself[n] = expf(lrelu02(asrc[n] + adst[n]));
  }
}

// ---------------- CSR aggregate (fp16 gathers, precomputed exps) ----------------

template<bool DOELU>
__global__ __launch_bounds__(256) void gat_aggregate4(const __half* __restrict__ hH, const float* __restrict__ exf,
                                                       const float* __restrict__ exself,
                                                       const int* __restrict__ row_ptr, const int* __restrict__ col,
                                                       const float* __restrict__ bias, float* __restrict__ out){
  int lane = threadIdx.x & 63;
  int wid = threadIdx.x >> 6;
  int d = blockIdx.x * 4 + wid;
  if (d >= NODES) return;
  int q = lane >> 4;        // head of this lane's 4 channels
  int co = lane * 4;        // channel offset in [0,256)

  // self loop
  float ex = exself[d * 4 + q];
  uint2 hv = *(const uint2*)(hH + (size_t)d * 256 + co);
  __half2 p0 = *(__half2*)&hv.x, p1 = *(__half2*)&hv.y;
  float2 f0 = __half22float2(p0), f1 = __half22float2(p1);
  float4 acc = make_float4(ex * f0.x, ex * f0.y, ex * f1.x, ex * f1.y);
  float den = ex;

  int e0 = row_ptr[d], e1 = row_ptr[d + 1];
  const __half* hbase = hH + co;
  for (int e = e0; e < e1; ++e){
    int s = col[e];
    ex = exf[(size_t)e * 4 + q];
    hv = *(const uint2*)(hbase + (size_t)s * 256);
    p0 = *(__half2*)&hv.x; p1 = *(__half2*)&hv.y;
    f0 = __half22float2(p0); f1 = __half22float2(p1);
    acc.x += ex * f0.x; acc.y += ex * f0.y; acc.z += ex * f1.x; acc.w += ex * f1.y;
    den += ex;
  }

  float inv = 1.f / (den + 1e-16f);
  float4 b4 = *(const float4*)&bias[co];
  float4 o = make_float4(acc.x * inv + b4.x, acc.y * inv + b4.y, acc.z * inv + b4.z, acc.w * inv + b4.w);
  if (DOELU){
    o.x = o.x > 0.f ? o.x : expm1f(o.x);
    o.y = o.y > 0.f ? o.y : expm1f(o.y);
    o.z = o.z > 0.f ? o.z : expm1f(o.z);
    o.w = o.w > 0.f ? o.w : expm1f(o.w);
  }
  *(float4*)&out[(size_t)d * 256 + co] = o;
}

__global__ __launch_bounds__(256) void gat_aggregate1(const __half* __restrict__ hH, const float* __restrict__ exf,
                                                       const float* __restrict__ exself,
                                                       const int* __restrict__ row_ptr, const int* __restrict__ col,
                                                       const float* __restrict__ bias, float* __restrict__ out){
  int lane = threadIdx.x & 63;
  int wid = threadIdx.x >> 6;
  int d = blockIdx.x * 4 + wid;
  if (d >= NODES) return;

  float ex = exself[d];
  float acc = ex * __half2float(hH[(size_t)d * 64 + lane]);
  float den = ex;

  int e0 = row_ptr[d], e1 = row_ptr[d + 1];
  const __half* hbase = hH + lane;
  for (int e = e0; e < e1; ++e){
    int s = col[e];
    ex = exf[e];
    acc += ex * __half2float(hbase[(size_t)s * 64]);
    den += ex;
  }
  out[(size_t)d * 64 + lane] = acc / (den + 1e-16f) + bias[lane];
}

// ---------------- launch ----------------

extern "C" void kernel_launch(void* const* d_in, const int* in_sizes, int n_in,
                              void* d_out, int out_size, void* d_ws, size_t ws_size,
                              hipStream_t stream) {
  const float* x   = (const float*)d_in[0];
  const int*   ei  = (const int*)  d_in[1];
  const float* W0  = (const float*)d_in[2];
  const float* as0 = (const float*)d_in[3];
  const float* ad0 = (const float*)d_in[4];
  const float* b0  = (const float*)d_in[5];
  const float* W1  = (const float*)d_in[6];
  const float* as1 = (const float*)d_in[7];
  const float* ad1 = (const float*)d_in[8];
  const float* b1  = (const float*)d_in[9];
  const float* W2  = (const float*)d_in[10];
  const float* as2 = (const float*)d_in[11];
  const float* ad2 = (const float*)d_in[12];
  const float* b2  = (const float*)d_in[13];
  float* out = (float*)d_out;

  auto al = [](size_t v){ return (v + 255) & ~(size_t)255; };
  char* p = (char*)d_ws;
  int*    row_ptr = (int*)p;    p += al((NODES + 1) * sizeof(int));
  int*    cnt     = (int*)p;    p += al(NODES * sizeof(int));
  int*    bsums   = (int*)p;    p += al(64 * sizeof(int));
  int*    col     = (int*)p;    p += al(EDGES * sizeof(int));
  int*    dstarr  = (int*)p;    p += al(EDGES * sizeof(int));
  float*  asrc    = (float*)p;  p += al(NODES * 4 * sizeof(float));
  float*  adst    = (float*)p;  p += al(NODES * 4 * sizeof(float));
  float*  exf     = (float*)p;  p += al((size_t)EDGES * 4 * sizeof(float));
  float*  exself  = (float*)p;  p += al(NODES * 4 * sizeof(float));
  float*  actb    = (float*)p;  p += al((size_t)NODES * 256 * sizeof(float));
  __half* hH      = (__half*)p; p += al((size_t)NODES * 256 * sizeof(__half));

  // ---- CSR build (by dst) ----
  gat_zero<<<(NODES + 255) / 256, 256, 0, stream>>>(cnt, NODES);
  gat_hist<<<(EDGES + 255) / 256, 256, 0, stream>>>(ei, cnt);
  gat_blocksum<<<NB_SCAN, 256, 0, stream>>>(cnt, bsums);
  gat_scan_bsums<<<1, 64, 0, stream>>>(bsums, NB_SCAN);
  gat_rowptr<<<NB_SCAN, 256, 0, stream>>>(cnt, bsums, row_ptr);
  gat_scatter<<<(EDGES + 255) / 256, 256, 0, stream>>>(ei, row_ptr, cnt, col, dstarr);

  const int nodeBlocks = (NODES + 3) / 4;
  const int edgeNodeBlocks = (EDGES + NODES + 255) / 256;

  // ---- Layer 0: x[50000,64] @ W0[64,256] ----
  gat_gemm_h<<<dim3(4, (NODES + 63) / 64), 256, 0, stream>>>(x, W0, hH, NODES, 64, 256);
  gat_attn<4><<<nodeBlocks, 256, 0, stream>>>(hH, as0, ad0, asrc, adst, NODES);
  gat_edge_exp4<<<edgeNodeBlocks, 256, 0, stream>>>(col, dstarr, asrc, adst, exf, exself);
  gat_aggregate4<true><<<nodeBlocks, 256, 0, stream>>>(hH, exf, exself, row_ptr, col, b0, actb);

  // ---- Layer 1: actb[50000,256] @ W1[256,256] ----
  gat_gemm_h<<<dim3(4, (NODES + 63) / 64), 256, 0, stream>>>(actb, W1, hH, NODES, 256, 256);
  gat_attn<4><<<nodeBlocks, 256, 0, stream>>>(hH, as1, ad1, asrc, adst, NODES);
  gat_edge_exp4<<<edgeNodeBlocks, 256, 0, stream>>>(col, dstarr, asrc, adst, exf, exself);
  gat_aggregate4<true><<<nodeBlocks, 256, 0, stream>>>(hH, exf, exself, row_ptr, col, b1, actb);

  // ---- Layer 2: actb[50000,256] @ W2[256,64], 1 head, no ELU ----
  gat_gemm_h<<<dim3(1, (NODES + 63) / 64), 256, 0, stream>>>(actb, W2, hH, NODES, 256, 64);
  gat_attn<1><<<nodeBlocks, 256, 0, stream>>>(hH, as2, ad2, asrc, adst, NODES);
  gat_edge_exp1<<<edgeNodeBlocks, 256, 0, stream>>>(col, dstarr, asrc, adst, exf, exself);
  gat_aggregate1<<<nodeBlocks, 256, 0, stream>>>(hH, exf, exself, row_ptr, col, b2, out);
}

// Round 3
// 400.460 us; speedup vs baseline: 1.7828x; 1.5729x over previous
//
#include <hip/hip_runtime.h>
#include <hip/hip_fp16.h>
#include <math.h>

#define NODES 50000
#define EDGES 800000
#define NB_SCAN ((NODES + 1023) / 1024)

typedef __attribute__((ext_vector_type(8))) _Float16 f16x8;
typedef __attribute__((ext_vector_type(4))) _Float16 f16x4;
typedef __attribute__((ext_vector_type(4))) float f32x4;

__device__ __forceinline__ float lrelu02(float x){ return x > 0.f ? x : 0.2f * x; }

// ---------------- CSR build ----------------

__global__ __launch_bounds__(256) void gat_zero(int* __restrict__ p, int n){
  int i = blockIdx.x * 256 + threadIdx.x;
  if (i < n) p[i] = 0;
}

__global__ __launch_bounds__(256) void gat_hist(const int* __restrict__ ei, int* __restrict__ cnt){
  int e = blockIdx.x * 256 + threadIdx.x;
  if (e < EDGES) atomicAdd(&cnt[ei[EDGES + e]], 1);
}

__global__ __launch_bounds__(256) void gat_blocksum(const int* __restrict__ cnt, int* __restrict__ bsums){
  __shared__ int sd[256];
  int t = threadIdx.x, b = blockIdx.x;
  int base = b * 1024 + t * 4, s = 0;
  #pragma unroll
  for (int j = 0; j < 4; j++){ int i = base + j; if (i < NODES) s += cnt[i]; }
  sd[t] = s; __syncthreads();
  for (int o = 128; o > 0; o >>= 1){ if (t < o) sd[t] += sd[t + o]; __syncthreads(); }
  if (t == 0) bsums[b] = sd[0];
}

__global__ void gat_scan_bsums(int* bsums, int nb){
  if (threadIdx.x == 0 && blockIdx.x == 0){
    int run = 0;
    for (int i = 0; i < nb; i++){ int v = bsums[i]; bsums[i] = run; run += v; }
  }
}

__global__ __launch_bounds__(256) void gat_rowptr(int* __restrict__ cnt, const int* __restrict__ bsums,
                                                  int* __restrict__ row_ptr){
  __shared__ int sd[256];
  int t = threadIdx.x, b = blockIdx.x;
  int base = b * 1024 + t * 4;
  int c[4]; int s = 0;
  #pragma unroll
  for (int j = 0; j < 4; j++){
    int i = base + j;
    c[j] = (i < NODES) ? cnt[i] : 0;
    s += c[j];
    if (i < NODES) cnt[i] = 0;   // reset for scatter fill counters
  }
  sd[t] = s; __syncthreads();
  for (int o = 1; o < 256; o <<= 1){
    int v = (t >= o) ? sd[t - o] : 0;
    __syncthreads();
    if (t >= o) sd[t] += v;
    __syncthreads();
  }
  int off = bsums[b] + sd[t] - s;
  #pragma unroll
  for (int j = 0; j < 4; j++){
    int i = base + j;
    if (i < NODES){ row_ptr[i] = off; off += c[j]; }
  }
  if (b == 0 && t == 0) row_ptr[NODES] = EDGES;
}

__global__ __launch_bounds__(256) void gat_scatter(const int* __restrict__ ei, const int* __restrict__ row_ptr,
                                                    int* __restrict__ fill, int* __restrict__ col){
  int e = blockIdx.x * 256 + threadIdx.x;
  if (e < EDGES){
    int s = ei[e], d = ei[EDGES + e];
    int pos = row_ptr[d] + atomicAdd(&fill[d], 1);
    col[pos] = s;
  }
}

// ---------------- fp32 -> fp16 convert / W transpose ----------------

__global__ __launch_bounds__(256) void gat_cvt_h(const float* __restrict__ src, _Float16* __restrict__ dst, int n4){
  int i = blockIdx.x * 256 + threadIdx.x;
  if (i < n4){
    float4 v = *(const float4*)(src + (size_t)i * 4);
    f16x4 h = { (_Float16)v.x, (_Float16)v.y, (_Float16)v.z, (_Float16)v.w };
    *(f16x4*)(dst + (size_t)i * 4) = h;
  }
}

// Wt[n][k] = (half)W[k][n];  grid = (ceil(N/256), K)
__global__ __launch_bounds__(256) void gat_wt(const float* __restrict__ W, _Float16* __restrict__ Wt, int K, int N){
  int n = blockIdx.x * 256 + threadIdx.x;
  int k = blockIdx.y;
  if (n < N) Wt[(size_t)n * K + k] = (_Float16)W[(size_t)k * N + n];
}

// ---------------- MFMA fp16 GEMM: C[M,N] = A[M,K] @ W[K,N], Wt = W^T [N][K] ----------------
// block = 256 thr (4 waves), BM = 64 rows, full N per block (no A refetch).
// wave w owns cols [w*N/4, (w+1)*N/4): NT = N/64 tiles of 16 cols.

template<int K, int N>
__global__ __launch_bounds__(256) void gat_gemm_mfma(const _Float16* __restrict__ A, const _Float16* __restrict__ Wt,
                                                      _Float16* __restrict__ C, int M){
  constexpr int NT = N / 64;
  constexpr int LDT = 40;     // f16 stride: 80 B = 20 banks -> 2-way aliasing (free)
  __shared__ _Float16 As[64][LDT];
  __shared__ _Float16 Bs[N][LDT];

  int tid = threadIdx.x;
  int w = tid >> 6, l = tid & 63;
  int lg = l >> 4, lr = l & 15;
  int bm = blockIdx.x * 64;

  f32x4 acc[4][NT];
  #pragma unroll
  for (int m = 0; m < 4; m++)
    #pragma unroll
    for (int n = 0; n < NT; n++)
      acc[m][n] = (f32x4){0.f, 0.f, 0.f, 0.f};

  int ar = tid >> 2;
  int akc = (tid & 3) * 8;
  bool avalid = (bm + ar) < M;
  const _Float16* aptr = A + (size_t)(bm + ar) * K + akc;

  for (int k0 = 0; k0 < K; k0 += 32){
    float4 av = avalid ? *(const float4*)(aptr + k0) : make_float4(0.f, 0.f, 0.f, 0.f);
    __syncthreads();
    *(float4*)&As[ar][akc] = av;
    #pragma unroll
    for (int c = 0; c < N / 64; c++){
      int idx = c * 256 + tid;
      int n = idx >> 2, kc = (idx & 3) * 8;
      *(float4*)&Bs[n][kc] = *(const float4*)(Wt + (size_t)n * K + k0 + kc);
    }
    __syncthreads();

    f16x8 af[4], bf[NT];
    #pragma unroll
    for (int m = 0; m < 4; m++) af[m] = *(const f16x8*)&As[16 * m + lr][8 * lg];
    #pragma unroll
    for (int n = 0; n < NT; n++) bf[n] = *(const f16x8*)&Bs[w * (N / 4) + 16 * n + lr][8 * lg];
    #pragma unroll
    for (int m = 0; m < 4; m++)
      #pragma unroll
      for (int n = 0; n < NT; n++)
        acc[m][n] = __builtin_amdgcn_mfma_f32_16x16x32_f16(af[m], bf[n], acc[m][n], 0, 0, 0);
  }

  // C layout: col = lane&15, row = (lane>>4)*4 + j   [m89-verified]
  #pragma unroll
  for (int m = 0; m < 4; m++){
    #pragma unroll
    for (int j = 0; j < 4; j++){
      int row = bm + 16 * m + 4 * lg + j;
      if (row < M){
        #pragma unroll
        for (int n = 0; n < NT; n++)
          C[(size_t)row * N + w * (N / 4) + 16 * n + lr] = (_Float16)acc[m][n][j];
      }
    }
  }
}

// ---------------- attention coefficients from fp16 h ----------------

template<int H>
__global__ __launch_bounds__(256) void gat_attn(const _Float16* __restrict__ h, const float* __restrict__ a_src,
                                                 const float* __restrict__ a_dst,
                                                 float* __restrict__ asrc, float* __restrict__ adst, int N){
  int lane = threadIdx.x & 63;
  int wid = threadIdx.x >> 6;
  int n = blockIdx.x * 4 + wid;
  if (n >= N) return;
  const int HC = H * 64;
  #pragma unroll
  for (int q = 0; q < H; q++){
    float v = (float)h[(size_t)n * HC + q * 64 + lane];
    float s1 = v * a_src[q * 64 + lane];
    float s2 = v * a_dst[q * 64 + lane];
    #pragma unroll
    for (int o = 32; o > 0; o >>= 1){ s1 += __shfl_xor(s1, o); s2 += __shfl_xor(s2, o); }
    if (lane == 0){ asrc[n * H + q] = s1; adst[n * H + q] = s2; }
  }
}

// ---------------- CSR aggregate: fused exp + fp16 gathers ----------------

template<bool DOELU>
__global__ __launch_bounds__(256) void gat_aggregate4(const _Float16* __restrict__ hH, const float* __restrict__ asrc,
                                                       const float* __restrict__ adst,
                                                       const int* __restrict__ row_ptr, const int* __restrict__ col,
                                                       const float* __restrict__ bias, _Float16* __restrict__ out){
  int lane = threadIdx.x & 63;
  int wid = threadIdx.x >> 6;
  int d = blockIdx.x * 4 + wid;
  if (d >= NODES) return;
  int q = lane >> 4;        // head of this lane's 4 channels
  int co = lane * 4;        // channel offset in [0,256)

  float adq = adst[d * 4 + q];

  // self loop
  float ex = __expf(lrelu02(asrc[d * 4 + q] + adq));
  f16x4 hv = *(const f16x4*)(hH + (size_t)d * 256 + co);
  float4 acc = make_float4(ex * (float)hv[0], ex * (float)hv[1], ex * (float)hv[2], ex * (float)hv[3]);
  float den = ex;

  int e0 = row_ptr[d], e1 = row_ptr[d + 1];
  const _Float16* hbase = hH + co;
  int e = e0;
  for (; e + 2 <= e1; e += 2){
    int s0 = col[e], s1 = col[e + 1];
    float a0 = asrc[s0 * 4 + q], a1 = asrc[s1 * 4 + q];
    f16x4 h0 = *(const f16x4*)(hbase + (size_t)s0 * 256);
    f16x4 h1 = *(const f16x4*)(hbase + (size_t)s1 * 256);
    float ex0 = __expf(lrelu02(a0 + adq));
    float ex1 = __expf(lrelu02(a1 + adq));
    den += ex0 + ex1;
    acc.x += ex0 * (float)h0[0] + ex1 * (float)h1[0];
    acc.y += ex0 * (float)h0[1] + ex1 * (float)h1[1];
    acc.z += ex0 * (float)h0[2] + ex1 * (float)h1[2];
    acc.w += ex0 * (float)h0[3] + ex1 * (float)h1[3];
  }
  if (e < e1){
    int s0 = col[e];
    float a0 = asrc[s0 * 4 + q];
    f16x4 h0 = *(const f16x4*)(hbase + (size_t)s0 * 256);
    float ex0 = __expf(lrelu02(a0 + adq));
    den += ex0;
    acc.x += ex0 * (float)h0[0]; acc.y += ex0 * (float)h0[1];
    acc.z += ex0 * (float)h0[2]; acc.w += ex0 * (float)h0[3];
  }

  float inv = 1.f / (den + 1e-16f);
  float4 b4 = *(const float4*)&bias[co];
  float4 o = make_float4(acc.x * inv + b4.x, acc.y * inv + b4.y, acc.z * inv + b4.z, acc.w * inv + b4.w);
  if (DOELU){
    o.x = o.x > 0.f ? o.x : expm1f(o.x);
    o.y = o.y > 0.f ? o.y : expm1f(o.y);
    o.z = o.z > 0.f ? o.z : expm1f(o.z);
    o.w = o.w > 0.f ? o.w : expm1f(o.w);
  }
  f16x4 oh = { (_Float16)o.x, (_Float16)o.y, (_Float16)o.z, (_Float16)o.w };
  *(f16x4*)(out + (size_t)d * 256 + co) = oh;
}

__global__ __launch_bounds__(256) void gat_aggregate1(const _Float16* __restrict__ hH, const float* __restrict__ asrc,
                                                       const float* __restrict__ adst,
                                                       const int* __restrict__ row_ptr, const int* __restrict__ col,
                                                       const float* __restrict__ bias, float* __restrict__ out){
  int lane = threadIdx.x & 63;
  int wid = threadIdx.x >> 6;
  int d = blockIdx.x * 4 + wid;
  if (d >= NODES) return;

  float adq = adst[d];
  float ex = __expf(lrelu02(asrc[d] + adq));
  float acc = ex * (float)hH[(size_t)d * 64 + lane];
  float den = ex;

  int e0 = row_ptr[d], e1 = row_ptr[d + 1];
  const _Float16* hbase = hH + lane;
  int e = e0;
  for (; e + 2 <= e1; e += 2){
    int s0 = col[e], s1 = col[e + 1];
    float a0 = asrc[s0], a1 = asrc[s1];
    float v0 = (float)hbase[(size_t)s0 * 64];
    float v1 = (float)hbase[(size_t)s1 * 64];
    float ex0 = __expf(lrelu02(a0 + adq));
    float ex1 = __expf(lrelu02(a1 + adq));
    den += ex0 + ex1;
    acc += ex0 * v0 + ex1 * v1;
  }
  if (e < e1){
    int s0 = col[e];
    float ex0 = __expf(lrelu02(asrc[s0] + adq));
    den += ex0;
    acc += ex0 * (float)hbase[(size_t)s0 * 64];
  }
  out[(size_t)d * 64 + lane] = acc / (den + 1e-16f) + bias[lane];
}

// ---------------- launch ----------------

extern "C" void kernel_launch(void* const* d_in, const int* in_sizes, int n_in,
                              void* d_out, int out_size, void* d_ws, size_t ws_size,
                              hipStream_t stream) {
  const float* x   = (const float*)d_in[0];
  const int*   ei  = (const int*)  d_in[1];
  const float* W0  = (const float*)d_in[2];
  const float* as0 = (const float*)d_in[3];
  const float* ad0 = (const float*)d_in[4];
  const float* b0  = (const float*)d_in[5];
  const float* W1  = (const float*)d_in[6];
  const float* as1 = (const float*)d_in[7];
  const float* ad1 = (const float*)d_in[8];
  const float* b1  = (const float*)d_in[9];
  const float* W2  = (const float*)d_in[10];
  const float* as2 = (const float*)d_in[11];
  const float* ad2 = (const float*)d_in[12];
  const float* b2  = (const float*)d_in[13];
  float* out = (float*)d_out;

  auto al = [](size_t v){ return (v + 255) & ~(size_t)255; };
  char* p = (char*)d_ws;
  int*      row_ptr = (int*)p;      p += al((NODES + 1) * sizeof(int));
  int*      cnt     = (int*)p;      p += al(NODES * sizeof(int));
  int*      bsums   = (int*)p;      p += al(64 * sizeof(int));
  int*      col     = (int*)p;      p += al(EDGES * sizeof(int));
  float*    asrc    = (float*)p;    p += al(NODES * 4 * sizeof(float));
  float*    adst    = (float*)p;    p += al(NODES * 4 * sizeof(float));
  _Float16* xh      = (_Float16*)p; p += al((size_t)NODES * 64 * sizeof(_Float16));
  _Float16* hH      = (_Float16*)p; p += al((size_t)NODES * 256 * sizeof(_Float16));
  _Float16* actb    = (_Float16*)p; p += al((size_t)NODES * 256 * sizeof(_Float16));
  _Float16* Wt0     = (_Float16*)p; p += al(256 * 64 * sizeof(_Float16));
  _Float16* Wt1     = (_Float16*)p; p += al(256 * 256 * sizeof(_Float16));
  _Float16* Wt2     = (_Float16*)p; p += al(64 * 256 * sizeof(_Float16));

  // ---- prep: conversions / transposes ----
  gat_cvt_h<<<(NODES * 64 / 4 + 255) / 256, 256, 0, stream>>>(x, xh, NODES * 64 / 4);
  gat_wt<<<dim3(1, 64), 256, 0, stream>>>(W0, Wt0, 64, 256);
  gat_wt<<<dim3(1, 256), 256, 0, stream>>>(W1, Wt1, 256, 256);
  gat_wt<<<dim3(1, 256), 256, 0, stream>>>(W2, Wt2, 256, 64);

  // ---- CSR build (by dst) ----
  gat_zero<<<(NODES + 255) / 256, 256, 0, stream>>>(cnt, NODES);
  gat_hist<<<(EDGES + 255) / 256, 256, 0, stream>>>(ei, cnt);
  gat_blocksum<<<NB_SCAN, 256, 0, stream>>>(cnt, bsums);
  gat_scan_bsums<<<1, 64, 0, stream>>>(bsums, NB_SCAN);
  gat_rowptr<<<NB_SCAN, 256, 0, stream>>>(cnt, bsums, row_ptr);
  gat_scatter<<<(EDGES + 255) / 256, 256, 0, stream>>>(ei, row_ptr, cnt, col);

  const int nodeBlocks = (NODES + 3) / 4;
  const int gemmBlocks = (NODES + 63) / 64;

  // ---- Layer 0: xh[50000,64] @ W0 -> hH[50000,256] ----
  gat_gemm_mfma<64, 256><<<gemmBlocks, 256, 0, stream>>>(xh, Wt0, hH, NODES);
  gat_attn<4><<<nodeBlocks, 256, 0, stream>>>(hH, as0, ad0, asrc, adst, NODES);
  gat_aggregate4<true><<<nodeBlocks, 256, 0, stream>>>(hH, asrc, adst, row_ptr, col, b0, actb);

  // ---- Layer 1: actb[50000,256] @ W1 -> hH[50000,256] ----
  gat_gemm_mfma<256, 256><<<gemmBlocks, 256, 0, stream>>>(actb, Wt1, hH, NODES);
  gat_attn<4><<<nodeBlocks, 256, 0, stream>>>(hH, as1, ad1, asrc, adst, NODES);
  gat_aggregate4<true><<<nodeBlocks, 256, 0, stream>>>(hH, asrc, adst, row_ptr, col, b1, actb);

  // ---- Layer 2: actb[50000,256] @ W2 -> hH[50000,64], 1 head ----
  gat_gemm_mfma<256, 64><<<gemmBlocks, 256, 0, stream>>>(actb, Wt2, hH, NODES);
  gat_attn<1><<<nodeBlocks, 256, 0, stream>>>(hH, as2, ad2, asrc, adst, NODES);
  gat_aggregate1<<<nodeBlocks, 256, 0, stream>>>(hH, asrc, adst, row_ptr, col, b2, out);
}